// Round 11
// baseline (1462.832 us; speedup 1.0000x reference)
//
#include <hip/hip_runtime.h>
#include <hip/hip_bf16.h>
#include <math.h>

#define H 768
#define B 256
#define T 100

typedef __attribute__((ext_vector_type(8))) short short8;
typedef __attribute__((ext_vector_type(16))) float f32x16;
typedef __attribute__((ext_vector_type(4))) float f32x4;
typedef unsigned long long u64;

static __device__ __forceinline__ float sigm(float x) {
    return 1.0f / (1.0f + __expf(-x));
}
static __device__ __forceinline__ float tanh_fast(float x) {
    return 1.0f - 2.0f / (__expf(2.0f * x) + 1.0f);
}

// ---------------- fused prep (single dispatch) ----------------
// grid dim3(3, 9808), block 256:
//   y <  3072 : weight row y  (Wc, Wcat, bias)
//   y <  3152 : Wp row (y-3072), zero-padded beyond 72
//   y <  3408 : A0 batch row (y-3152)
//   y <  9808 : sig zero chunk (y-3408): 6400 rows x 768 u64 = 39.3 MB
__global__ void prep_all(const float* __restrict__ src, const float* __restrict__ h0,
                         const float* __restrict__ Wih, const float* __restrict__ Whh,
                         const float* __restrict__ bih, const float* __restrict__ bhh,
                         const float* __restrict__ Wpost,
                         __hip_bfloat16* __restrict__ Wc,    // 3072 x 768 (Wih+Whh)
                         __hip_bfloat16* __restrict__ Wcat,  // 3072 x 1536 [Wih|Whh]
                         float* __restrict__ bias,           // 3072
                         __hip_bfloat16* __restrict__ Wp,    // 80 x 768
                         __hip_bfloat16* __restrict__ A0,    // 256 x 1536 [x0|h0]
                         u64* __restrict__ sig64)            // T*B*192 u64, zeroed
{
    const int bx = blockIdx.x;
    const int y  = blockIdx.y;
    const int k  = bx * 256 + threadIdx.x;
    if (y < 3072) {
        float a = Wih[y * H + k];
        float b = Whh[y * H + k];
        Wc[y * H + k] = __float2bfloat16(a + b);
        Wcat[y * 1536 + k] = __float2bfloat16(a);
        Wcat[y * 1536 + H + k] = __float2bfloat16(b);
        if (bx == 0 && threadIdx.x == 0) bias[y] = bih[y] + bhh[y];
    } else if (y < 3152) {
        int r = y - 3072;
        Wp[r * H + k] = (r < 72) ? __float2bfloat16(Wpost[r * H + k])
                                 : __float2bfloat16(0.0f);
    } else if (y < 3408) {
        int b = y - 3152;
        A0[b * 1536 + k] = __float2bfloat16(src[(b * 16 + 15) * H + k]);  // src[:, -1]
        A0[b * 1536 + H + k] = __float2bfloat16(h0[b * H + k]);
    } else {
        sig64[(size_t)(y - 3408) * 768 + k] = 0ull;
    }
}

// ---------------- persistent recurrence: steps 0..99 ----------------
// grid 256 blocks (8 mtg x 32 jg) x 192 threads (3 waves).
// Each wave: one 32x32x16-MFMA tile = 32 batches x 32 gate-rows (of the
// block's 96 = 24 j x 4 gates). B-frag pinned: 48 short8 = 192 regs/wave.
// SOUND pinning: grouped asm blocks, 8 loads + s_waitcnt vmcnt(0) INSIDE the
// asm, early-clobber outputs -> values defined at asm-exit (no async-output
// copy/spill hazard: that bug produced R10's NaN).
// Sync: data-is-signal (R9-proven). 2 barriers/step.
#define LDS_H_STRIDE  772    // shorts; 8B-aligned rows, R9-measured low conflicts
#define LDS_T0_STRIDE 1540   // shorts
#define XCH_STRIDE    33     // floats per gate-row (32 + 1 pad)

#define LDW8(n0,n1,n2,n3,n4,n5,n6,n7, p) \
    asm volatile("global_load_dwordx4 %0, %8, off\n\t" \
                 "global_load_dwordx4 %1, %8, off offset:32\n\t" \
                 "global_load_dwordx4 %2, %8, off offset:64\n\t" \
                 "global_load_dwordx4 %3, %8, off offset:96\n\t" \
                 "global_load_dwordx4 %4, %8, off offset:128\n\t" \
                 "global_load_dwordx4 %5, %8, off offset:160\n\t" \
                 "global_load_dwordx4 %6, %8, off offset:192\n\t" \
                 "global_load_dwordx4 %7, %8, off offset:224\n\t" \
                 "s_waitcnt vmcnt(0)" \
                 : "=&v"(n0),"=&v"(n1),"=&v"(n2),"=&v"(n3), \
                   "=&v"(n4),"=&v"(n5),"=&v"(n6),"=&v"(n7) \
                 : "v"(p))

#define KST(nm, idx) { \
    short8 a_ = *(const short8*)(&lds_h[arow * LDS_H_STRIDE + (idx) * 16 + half * 8]); \
    acc = __builtin_amdgcn_mfma_f32_32x32x16_bf16(a_, nm, acc, 0, 0, 0); }

static __device__ __forceinline__ bool sig_ok(u64 x) {
    return (unsigned short)x && (unsigned short)(x >> 16) &&
           (unsigned short)(x >> 32) && (unsigned short)(x >> 48);
}

__global__ __launch_bounds__(192, 1) void lstm_persist(
    const __hip_bfloat16* __restrict__ Wc,    // 3072 x 768 bf16 (Wih+Whh)
    const __hip_bfloat16* __restrict__ Wcat,  // 3072 x 1536 bf16 [Wih|Whh]
    const float* __restrict__ bias,           // 3072
    const float* __restrict__ c0in,           // B x H fp32
    const __hip_bfloat16* __restrict__ A0,    // 256 x 1536 [x0|h0]
    unsigned* sig)                            // T x B x 384 u32 (~bf16 pairs), zeroed
{
    const int mtg  = blockIdx.x >> 5;    // batch group 0..7 (32 batches)
    const int jg   = blockIdx.x & 31;    // j group 0..31 (24 j values)
    const int tid  = threadIdx.x;        // 0..191
    const int lane = tid & 63;
    const int wave = tid >> 6;           // 0..2 (tile)
    const int arow = lane & 31;          // A row (batch) / B col (gate-row)
    const int half = lane >> 5;          // k-half selector
    const int r    = wave * 32 + arow;   // gate-row within block's 96-row set
    const int g    = r / 24;             // gate 0..3
    const int j_l  = r % 24;             // local j 0..23
    const int Wrow = g * H + jg * 24 + j_l;   // row in Wc/Wcat

    __shared__ short lds_h[32 * LDS_T0_STRIDE];   // 98560 B (t0; t>=1 stride 772)
    __shared__ float xch[96 * XCH_STRIDE];        // 12672 B gate exchange [r][m]

    // ---- pin B-frag weight slice in regs: 48 x short8 = 192 regs (sound) ----
    const short* wptr = (const short*)Wc + (size_t)Wrow * H + half * 8;
    short8 w00,w01,w02,w03,w04,w05,w06,w07,w08,w09,w10,w11,
           w12,w13,w14,w15,w16,w17,w18,w19,w20,w21,w22,w23,
           w24,w25,w26,w27,w28,w29,w30,w31,w32,w33,w34,w35,
           w36,w37,w38,w39,w40,w41,w42,w43,w44,w45,w46,w47;
    LDW8(w00,w01,w02,w03,w04,w05,w06,w07, wptr);
    LDW8(w08,w09,w10,w11,w12,w13,w14,w15, wptr + 128);
    LDW8(w16,w17,w18,w19,w20,w21,w22,w23, wptr + 256);
    LDW8(w24,w25,w26,w27,w28,w29,w30,w31, wptr + 384);
    LDW8(w32,w33,w34,w35,w36,w37,w38,w39, wptr + 512);
    LDW8(w40,w41,w42,w43,w44,w45,w46,w47, wptr + 640);

    // ---- cell-role state: thread = 1 j column x 4 batches ----
    const int cj   = tid % 24;           // local j
    const int cb   = tid / 24;           // batch quad 0..7
    const int jglob = jg * 24 + cj;
    const int bglob0 = mtg * 32 + cb * 4;
    const float bi = bias[0 * H + jglob];
    const float bf = bias[1 * H + jglob];
    const float bg = bias[2 * H + jglob];
    const float bo = bias[3 * H + jglob];
    float cv[4];
#pragma unroll
    for (int rr = 0; rr < 4; ++rr)
        cv[rr] = c0in[(size_t)(bglob0 + rr) * H + jglob];

    const u64* sig64c = (const u64*)sig;

    for (int t = 0; t < T; ++t) {
        f32x16 acc;
#pragma unroll
        for (int i = 0; i < 16; ++i) acc[i] = 0.f;

        if (t == 0) {
            // ---- stage A0[32 rows][1536] -> LDS (plain loads; prior kernel) ----
            const u64* a8 = (const u64*)((const short*)A0 + (size_t)(mtg * 32) * 1536);
#pragma unroll
            for (int i = 0; i < 64; ++i) {
                int idx = tid + i * 192;      // 0..12287 (32 rows x 384 u64)
                int br  = idx / 384;
                int ch  = idx % 384;
                *(u64*)&lds_h[br * LDS_T0_STRIDE + ch * 4] = a8[(size_t)br * 384 + ch];
            }
            __syncthreads();   // (B)

            // ---- K=1536 GEMM streaming Wcat (one-time) ----
            const short* wq = (const short*)Wcat + (size_t)Wrow * 1536 + half * 8;
            for (int kk = 0; kk < 96; ++kk) {
                short8 a_ = *(const short8*)(&lds_h[arow * LDS_T0_STRIDE + kk * 16 + half * 8]);
                short8 b_ = *(const short8*)(wq + kk * 16);
                acc = __builtin_amdgcn_mfma_f32_32x32x16_bf16(a_, b_, acc, 0, 0, 0);
            }
        } else {
            // ---- poll+stage h(t-1): thread owns word tid of all 32 rows ----
            const u64* hb = sig64c + ((size_t)(t - 1) * B + (size_t)(mtg * 32)) * 192;
            unsigned pending = 0xFFFFFFFFu;
#pragma unroll
            for (int i = 0; i < 32; ++i) {
                u64 x = __hip_atomic_load(hb + (size_t)i * 192 + tid,
                                          __ATOMIC_RELAXED, __HIP_MEMORY_SCOPE_AGENT);
                if (sig_ok(x)) {
                    *(u64*)&lds_h[i * LDS_H_STRIDE + tid * 4] = ~x;
                    pending &= ~(1u << i);
                }
            }
            int guard = 0;
            while (pending && ++guard < (1 << 22)) {
                __builtin_amdgcn_s_sleep(1);
#pragma unroll
                for (int i = 0; i < 32; ++i) {
                    if (pending & (1u << i)) {
                        u64 x = __hip_atomic_load(hb + (size_t)i * 192 + tid,
                                                  __ATOMIC_RELAXED, __HIP_MEMORY_SCOPE_AGENT);
                        if (sig_ok(x)) {
                            *(u64*)&lds_h[i * LDS_H_STRIDE + tid * 4] = ~x;
                            pending &= ~(1u << i);
                        }
                    }
                }
            }
            __syncthreads();   // (B) lds_h ready

            // ---- K=768 GEMM vs pinned weights ----
            KST(w00,0)  KST(w01,1)  KST(w02,2)  KST(w03,3)  KST(w04,4)  KST(w05,5)
            KST(w06,6)  KST(w07,7)  KST(w08,8)  KST(w09,9)  KST(w10,10) KST(w11,11)
            KST(w12,12) KST(w13,13) KST(w14,14) KST(w15,15) KST(w16,16) KST(w17,17)
            KST(w18,18) KST(w19,19) KST(w20,20) KST(w21,21) KST(w22,22) KST(w23,23)
            KST(w24,24) KST(w25,25) KST(w26,26) KST(w27,27) KST(w28,28) KST(w29,29)
            KST(w30,30) KST(w31,31) KST(w32,32) KST(w33,33) KST(w34,34) KST(w35,35)
            KST(w36,36) KST(w37,37) KST(w38,38) KST(w39,39) KST(w40,40) KST(w41,41)
            KST(w42,42) KST(w43,43) KST(w44,44) KST(w45,45) KST(w46,46) KST(w47,47)
        }

        // ---- exchange: xch[r][m] ; D layout m=(reg&3)+8*(reg>>2)+4*half ----
        {
            float* xr = &xch[(size_t)r * XCH_STRIDE + 4 * half];
#pragma unroll
            for (int reg = 0; reg < 16; ++reg)
                xr[(reg & 3) + 8 * (reg >> 2)] = acc[reg];
        }
        __syncthreads();   // (C) xch ready; all lds_h reads of this step done

        // ---- cell update + inverted-bf16 publish (store IS the signal) ----
        {
            unsigned mm[4];
#pragma unroll
            for (int rr = 0; rr < 4; ++rr) {
                const int m = cb * 4 + rr;
                float i0 = xch[(0 * 24 + cj) * XCH_STRIDE + m] + bi;
                float f0 = xch[(1 * 24 + cj) * XCH_STRIDE + m] + bf;
                float g0 = xch[(2 * 24 + cj) * XCH_STRIDE + m] + bg;
                float o0 = xch[(3 * 24 + cj) * XCH_STRIDE + m] + bo;
                float cn = sigm(f0) * cv[rr] + sigm(i0) * tanh_fast(g0);
                cv[rr] = cn;
                float hn = sigm(o0) * tanh_fast(cn);
                __hip_bfloat16 hbv = __float2bfloat16(hn);
                mm[rr] = (unsigned)(unsigned short)~(*(unsigned short*)&hbv);  // nonzero
            }
#pragma unroll
            for (int rr = 0; rr < 4; ++rr) {
                unsigned other = (unsigned)__shfl_xor((int)mm[rr], 1, 64);  // j partner
                if ((cj & 1) == 0) {
                    __hip_atomic_store(&sig[((size_t)t * B + (bglob0 + rr)) * 384 + (jglob >> 1)],
                                       mm[rr] | (other << 16),
                                       __ATOMIC_RELAXED, __HIP_MEMORY_SCOPE_AGENT);
                }
            }
        }
        // no barrier (D): (C) + next-step barrier (B) cover the WAR hazards.
    }
}

// ---------------- post projection (reads inverted sig) ----------------
__global__ __launch_bounds__(64) void proj(
    const short* __restrict__ Hs,            // (T*B) x 768 inverted bf16
    const __hip_bfloat16* __restrict__ Wp,   // 80 x H (padded bf16)
    const float* __restrict__ bpost,         // 72
    float* __restrict__ out)                 // B x T x 72
{
    const int mt = blockIdx.x;
    const int lane = threadIdx.x;
    const int col = lane & 15;
    const int quad = lane >> 4;

    const short* Ap = Hs + (size_t)(mt * 16 + col) * H + quad * 8;
    const short* Wb = (const short*)Wp;

    f32x4 acc[5];
#pragma unroll
    for (int nt = 0; nt < 5; ++nt) acc[nt] = (f32x4){0.f, 0.f, 0.f, 0.f};

    for (int k = 0; k < H; k += 32) {
        short8 a = ~(*(const short8*)(Ap + k));   // un-invert
#pragma unroll
        for (int nt = 0; nt < 5; ++nt) {
            short8 b = *(const short8*)(Wb + (size_t)(nt * 16 + col) * H + quad * 8 + k);
            acc[nt] = __builtin_amdgcn_mfma_f32_16x16x32_bf16(a, b, acc[nt], 0, 0, 0);
        }
    }

#pragma unroll
    for (int nt = 0; nt < 5; ++nt) {
        const int o = nt * 16 + col;
        if (o < 72) {
            const float bb = bpost[o];
#pragma unroll
            for (int r = 0; r < 4; ++r) {
                const int m = mt * 16 + quad * 4 + r;
                const int t = m >> 8;        // row = t*256 + b
                const int b = m & 255;
                out[((size_t)b * T + t) * 72 + o] = acc[nt][r] + bb;
            }
        }
    }
}

// ---------------- launch ----------------

extern "C" void kernel_launch(void* const* d_in, const int* in_sizes, int n_in,
                              void* d_out, int out_size, void* d_ws, size_t ws_size,
                              hipStream_t stream) {
    const float* src   = (const float*)d_in[0];
    const float* h0    = (const float*)d_in[2];
    const float* c0    = (const float*)d_in[3];
    const float* Wih   = (const float*)d_in[4];
    const float* Whh   = (const float*)d_in[5];
    const float* bih   = (const float*)d_in[6];
    const float* bhh   = (const float*)d_in[7];
    const float* Wpost = (const float*)d_in[8];
    const float* bpost = (const float*)d_in[9];
    float* out = (float*)d_out;

    char* ws = (char*)d_ws;
    __hip_bfloat16* Wcat = (__hip_bfloat16*)(ws + 0);          //  9,437,184 B
    __hip_bfloat16* Wc   = (__hip_bfloat16*)(ws + 9437184);    //  4,718,592 B
    float*          bias = (float*)(ws + 14155776);            //     12,288 B
    __hip_bfloat16* Wp   = (__hip_bfloat16*)(ws + 14168064);   //    122,880 B
    __hip_bfloat16* A0   = (__hip_bfloat16*)(ws + 14290944);   //    786,432 B
    unsigned*       sig  = (unsigned*)(ws + 15863808);         // 39,321,600 B

    // all prep (weights, Wp, A0, sig zero) in one dispatch
    prep_all<<<dim3(3, 9808), 256, 0, stream>>>(src, h0, Wih, Whh, bih, bhh, Wpost,
                                                Wc, Wcat, bias, Wp, A0, (u64*)sig);

    // steps 0..99 in one persistent kernel (32x32 tiles, sound pinning)
    lstm_persist<<<256, 192, 0, stream>>>(Wc, Wcat, bias, c0, A0, sig);

    proj<<<1600, 64, 0, stream>>>((const short*)sig, Wp, bpost, out);
}

// Round 12
// 1009.478 us; speedup vs baseline: 1.4491x; 1.4491x over previous
//
#include <hip/hip_runtime.h>
#include <hip/hip_bf16.h>
#include <math.h>

#define H 768
#define B 256
#define T 100

typedef __attribute__((ext_vector_type(8))) short short8;
typedef __attribute__((ext_vector_type(16))) float f32x16;
typedef __attribute__((ext_vector_type(4))) float f32x4;
typedef unsigned long long u64;

static __device__ __forceinline__ float sigm(float x) {
    return 1.0f / (1.0f + __expf(-x));
}
static __device__ __forceinline__ float tanh_fast(float x) {
    return 1.0f - 2.0f / (__expf(2.0f * x) + 1.0f);
}

// ---------------- fused prep (single dispatch) ----------------
// grid dim3(3, 9808), block 256:
//   y <  3072 : weight row y  (Wc, Wcat, bias)
//   y <  3152 : Wp row (y-3072), zero-padded beyond 72
//   y <  3408 : A0 batch row (y-3152)
//   y <  9808 : sig zero chunk (y-3408): 6400 rows x 768 u64 = 39.3 MB
__global__ void prep_all(const float* __restrict__ src, const float* __restrict__ h0,
                         const float* __restrict__ Wih, const float* __restrict__ Whh,
                         const float* __restrict__ bih, const float* __restrict__ bhh,
                         const float* __restrict__ Wpost,
                         __hip_bfloat16* __restrict__ Wc,    // 3072 x 768 (Wih+Whh)
                         __hip_bfloat16* __restrict__ Wcat,  // 3072 x 1536 [Wih|Whh]
                         float* __restrict__ bias,           // 3072
                         __hip_bfloat16* __restrict__ Wp,    // 80 x 768
                         __hip_bfloat16* __restrict__ A0,    // 256 x 1536 [x0|h0]
                         u64* __restrict__ sig64)            // T*B*192 u64, zeroed
{
    const int bx = blockIdx.x;
    const int y  = blockIdx.y;
    const int k  = bx * 256 + threadIdx.x;
    if (y < 3072) {
        float a = Wih[y * H + k];
        float b = Whh[y * H + k];
        Wc[y * H + k] = __float2bfloat16(a + b);
        Wcat[y * 1536 + k] = __float2bfloat16(a);
        Wcat[y * 1536 + H + k] = __float2bfloat16(b);
        if (bx == 0 && threadIdx.x == 0) bias[y] = bih[y] + bhh[y];
    } else if (y < 3152) {
        int r = y - 3072;
        Wp[r * H + k] = (r < 72) ? __float2bfloat16(Wpost[r * H + k])
                                 : __float2bfloat16(0.0f);
    } else if (y < 3408) {
        int b = y - 3152;
        A0[b * 1536 + k] = __float2bfloat16(src[(b * 16 + 15) * H + k]);  // src[:, -1]
        A0[b * 1536 + H + k] = __float2bfloat16(h0[b * H + k]);
    } else {
        sig64[(size_t)(y - 3408) * 768 + k] = 0ull;
    }
}

// ---------------- persistent recurrence: steps 0..99 ----------------
// grid 256 blocks (8 mtg x 32 jg) x 192 threads (3 waves).
// Each wave: one 32x32x16-MFMA tile = 32 batches x 32 gate-rows.
// B-frag pinned: 48 short8 = 192 regs/wave via SOUND grouped-asm loads.
// R12 fixes vs R11 (both latency-serialization bugs):
//  (1) batched polling: all 32 sig words loaded into regs before checking
//      (1 LLC RT per sweep instead of 32 serial RTs);
//  (2) 4 independent MFMA accumulator chains (issue-limited, not
//      latency-limited, at 1 wave/SIMD).
#define LDS_H_STRIDE  772    // shorts; 8B-aligned rows, low conflicts (R9/R11)
#define LDS_T0_STRIDE 1540   // shorts
#define XCH_STRIDE    33     // floats per gate-row (32 + 1 pad)

#define LDW8(n0,n1,n2,n3,n4,n5,n6,n7, p) \
    asm volatile("global_load_dwordx4 %0, %8, off\n\t" \
                 "global_load_dwordx4 %1, %8, off offset:32\n\t" \
                 "global_load_dwordx4 %2, %8, off offset:64\n\t" \
                 "global_load_dwordx4 %3, %8, off offset:96\n\t" \
                 "global_load_dwordx4 %4, %8, off offset:128\n\t" \
                 "global_load_dwordx4 %5, %8, off offset:160\n\t" \
                 "global_load_dwordx4 %6, %8, off offset:192\n\t" \
                 "global_load_dwordx4 %7, %8, off offset:224\n\t" \
                 "s_waitcnt vmcnt(0)" \
                 : "=&v"(n0),"=&v"(n1),"=&v"(n2),"=&v"(n3), \
                   "=&v"(n4),"=&v"(n5),"=&v"(n6),"=&v"(n7) \
                 : "v"(p))

// chain = idx & 3 -> 4 independent accumulation chains
#define KST(ac, nm, idx) { \
    short8 a_ = *(const short8*)(&lds_h[arow * LDS_H_STRIDE + (idx) * 16 + half * 8]); \
    ac = __builtin_amdgcn_mfma_f32_32x32x16_bf16(a_, nm, ac, 0, 0, 0); }

static __device__ __forceinline__ bool sig_ok(u64 x) {
    return (unsigned short)x && (unsigned short)(x >> 16) &&
           (unsigned short)(x >> 32) && (unsigned short)(x >> 48);
}

__global__ __launch_bounds__(192, 1) void lstm_persist(
    const __hip_bfloat16* __restrict__ Wc,    // 3072 x 768 bf16 (Wih+Whh)
    const __hip_bfloat16* __restrict__ Wcat,  // 3072 x 1536 bf16 [Wih|Whh]
    const float* __restrict__ bias,           // 3072
    const float* __restrict__ c0in,           // B x H fp32
    const __hip_bfloat16* __restrict__ A0,    // 256 x 1536 [x0|h0]
    unsigned* sig)                            // T x B x 384 u32 (~bf16 pairs), zeroed
{
    const int mtg  = blockIdx.x >> 5;    // batch group 0..7 (32 batches)
    const int jg   = blockIdx.x & 31;    // j group 0..31 (24 j values)
    const int tid  = threadIdx.x;        // 0..191
    const int lane = tid & 63;
    const int wave = tid >> 6;           // 0..2 (tile)
    const int arow = lane & 31;          // A row (batch) / B col (gate-row)
    const int half = lane >> 5;          // k-half selector
    const int r    = wave * 32 + arow;   // gate-row within block's 96-row set
    const int g    = r / 24;             // gate 0..3
    const int j_l  = r % 24;             // local j 0..23
    const int Wrow = g * H + jg * 24 + j_l;   // row in Wc/Wcat

    __shared__ short lds_h[32 * LDS_T0_STRIDE];   // 98560 B (t0; t>=1 stride 772)
    __shared__ float xch[96 * XCH_STRIDE];        // 12672 B gate exchange [r][m]

    // ---- pin B-frag weight slice in regs: 48 x short8 = 192 regs (sound) ----
    const short* wptr = (const short*)Wc + (size_t)Wrow * H + half * 8;
    short8 w00,w01,w02,w03,w04,w05,w06,w07,w08,w09,w10,w11,
           w12,w13,w14,w15,w16,w17,w18,w19,w20,w21,w22,w23,
           w24,w25,w26,w27,w28,w29,w30,w31,w32,w33,w34,w35,
           w36,w37,w38,w39,w40,w41,w42,w43,w44,w45,w46,w47;
    LDW8(w00,w01,w02,w03,w04,w05,w06,w07, wptr);
    LDW8(w08,w09,w10,w11,w12,w13,w14,w15, wptr + 128);
    LDW8(w16,w17,w18,w19,w20,w21,w22,w23, wptr + 256);
    LDW8(w24,w25,w26,w27,w28,w29,w30,w31, wptr + 384);
    LDW8(w32,w33,w34,w35,w36,w37,w38,w39, wptr + 512);
    LDW8(w40,w41,w42,w43,w44,w45,w46,w47, wptr + 640);

    // ---- cell-role state: thread = 1 j column x 4 batches ----
    const int cj   = tid % 24;           // local j
    const int cb   = tid / 24;           // batch quad 0..7
    const int jglob = jg * 24 + cj;
    const int bglob0 = mtg * 32 + cb * 4;
    const float bi = bias[0 * H + jglob];
    const float bf = bias[1 * H + jglob];
    const float bg = bias[2 * H + jglob];
    const float bo = bias[3 * H + jglob];
    float cv[4];
#pragma unroll
    for (int rr = 0; rr < 4; ++rr)
        cv[rr] = c0in[(size_t)(bglob0 + rr) * H + jglob];

    const u64* sig64c = (const u64*)sig;

    for (int t = 0; t < T; ++t) {
        f32x16 acc0, acc1, acc2, acc3;
#pragma unroll
        for (int i = 0; i < 16; ++i) { acc0[i]=0.f; acc1[i]=0.f; acc2[i]=0.f; acc3[i]=0.f; }

        if (t == 0) {
            // ---- stage A0[32 rows][1536] -> LDS (plain loads; prior kernel) ----
            const u64* a8 = (const u64*)((const short*)A0 + (size_t)(mtg * 32) * 1536);
#pragma unroll
            for (int i = 0; i < 64; ++i) {
                int idx = tid + i * 192;      // 0..12287 (32 rows x 384 u64)
                int br  = idx / 384;
                int ch  = idx % 384;
                *(u64*)&lds_h[br * LDS_T0_STRIDE + ch * 4] = a8[(size_t)br * 384 + ch];
            }
            __syncthreads();   // (B)

            // ---- K=1536 GEMM streaming Wcat (one-time, 4 chains) ----
            const short* wq = (const short*)Wcat + (size_t)Wrow * 1536 + half * 8;
            for (int kk = 0; kk < 96; kk += 4) {
#pragma unroll
                for (int q = 0; q < 4; ++q) {
                    short8 a_ = *(const short8*)(&lds_h[arow * LDS_T0_STRIDE + (kk+q) * 16 + half * 8]);
                    short8 b_ = *(const short8*)(wq + (kk+q) * 16);
                    f32x16* accp = (q==0)?&acc0:(q==1)?&acc1:(q==2)?&acc2:&acc3;
                    *accp = __builtin_amdgcn_mfma_f32_32x32x16_bf16(a_, b_, *accp, 0, 0, 0);
                }
            }
        } else {
            // ---- poll+stage h(t-1): BATCHED loads (1 LLC RT per sweep) ----
            const u64* hb = sig64c + ((size_t)(t - 1) * B + (size_t)(mtg * 32)) * 192;
            u64 x[32];
#pragma unroll
            for (int i = 0; i < 32; ++i)
                x[i] = __hip_atomic_load(hb + (size_t)i * 192 + tid,
                                         __ATOMIC_RELAXED, __HIP_MEMORY_SCOPE_AGENT);
            unsigned pending = 0xFFFFFFFFu;
#pragma unroll
            for (int i = 0; i < 32; ++i) {
                if (sig_ok(x[i])) {
                    *(u64*)&lds_h[i * LDS_H_STRIDE + tid * 4] = ~x[i];
                    pending &= ~(1u << i);
                }
            }
            int guard = 0;
            while (pending && ++guard < (1 << 20)) {
                __builtin_amdgcn_s_sleep(1);
#pragma unroll
                for (int i = 0; i < 32; ++i)
                    if (pending & (1u << i))
                        x[i] = __hip_atomic_load(hb + (size_t)i * 192 + tid,
                                                 __ATOMIC_RELAXED, __HIP_MEMORY_SCOPE_AGENT);
#pragma unroll
                for (int i = 0; i < 32; ++i) {
                    if ((pending & (1u << i)) && sig_ok(x[i])) {
                        *(u64*)&lds_h[i * LDS_H_STRIDE + tid * 4] = ~x[i];
                        pending &= ~(1u << i);
                    }
                }
            }
            __syncthreads();   // (B) lds_h ready

            // ---- K=768 GEMM vs pinned weights (4 independent chains) ----
            KST(acc0,w00,0)  KST(acc1,w01,1)  KST(acc2,w02,2)  KST(acc3,w03,3)
            KST(acc0,w04,4)  KST(acc1,w05,5)  KST(acc2,w06,6)  KST(acc3,w07,7)
            KST(acc0,w08,8)  KST(acc1,w09,9)  KST(acc2,w10,10) KST(acc3,w11,11)
            KST(acc0,w12,12) KST(acc1,w13,13) KST(acc2,w14,14) KST(acc3,w15,15)
            KST(acc0,w16,16) KST(acc1,w17,17) KST(acc2,w18,18) KST(acc3,w19,19)
            KST(acc0,w20,20) KST(acc1,w21,21) KST(acc2,w22,22) KST(acc3,w23,23)
            KST(acc0,w24,24) KST(acc1,w25,25) KST(acc2,w26,26) KST(acc3,w27,27)
            KST(acc0,w28,28) KST(acc1,w29,29) KST(acc2,w30,30) KST(acc3,w31,31)
            KST(acc0,w32,32) KST(acc1,w33,33) KST(acc2,w34,34) KST(acc3,w35,35)
            KST(acc0,w36,36) KST(acc1,w37,37) KST(acc2,w38,38) KST(acc3,w39,39)
            KST(acc0,w40,40) KST(acc1,w41,41) KST(acc2,w42,42) KST(acc3,w43,43)
            KST(acc0,w44,44) KST(acc1,w45,45) KST(acc2,w46,46) KST(acc3,w47,47)
        }

        f32x16 acc = (acc0 + acc1) + (acc2 + acc3);

        // ---- exchange: xch[r][m] ; D layout m=(reg&3)+8*(reg>>2)+4*half ----
        {
            float* xr = &xch[(size_t)r * XCH_STRIDE + 4 * half];
#pragma unroll
            for (int reg = 0; reg < 16; ++reg)
                xr[(reg & 3) + 8 * (reg >> 2)] = acc[reg];
        }
        __syncthreads();   // (C) xch ready; all lds_h reads of this step done

        // ---- cell update + inverted-bf16 publish (store IS the signal) ----
        {
            unsigned mm[4];
#pragma unroll
            for (int rr = 0; rr < 4; ++rr) {
                const int m = cb * 4 + rr;
                float i0 = xch[(0 * 24 + cj) * XCH_STRIDE + m] + bi;
                float f0 = xch[(1 * 24 + cj) * XCH_STRIDE + m] + bf;
                float g0 = xch[(2 * 24 + cj) * XCH_STRIDE + m] + bg;
                float o0 = xch[(3 * 24 + cj) * XCH_STRIDE + m] + bo;
                float cn = sigm(f0) * cv[rr] + sigm(i0) * tanh_fast(g0);
                cv[rr] = cn;
                float hn = sigm(o0) * tanh_fast(cn);
                __hip_bfloat16 hbv = __float2bfloat16(hn);
                mm[rr] = (unsigned)(unsigned short)~(*(unsigned short*)&hbv);  // nonzero
            }
#pragma unroll
            for (int rr = 0; rr < 4; ++rr) {
                unsigned other = (unsigned)__shfl_xor((int)mm[rr], 1, 64);  // j partner
                if ((cj & 1) == 0) {
                    __hip_atomic_store(&sig[((size_t)t * B + (bglob0 + rr)) * 384 + (jglob >> 1)],
                                       mm[rr] | (other << 16),
                                       __ATOMIC_RELAXED, __HIP_MEMORY_SCOPE_AGENT);
                }
            }
        }
        // no barrier (D): (C) + next-step barrier (B) cover the WAR hazards.
    }
}

// ---------------- post projection (reads inverted sig) ----------------
__global__ __launch_bounds__(64) void proj(
    const short* __restrict__ Hs,            // (T*B) x 768 inverted bf16
    const __hip_bfloat16* __restrict__ Wp,   // 80 x H (padded bf16)
    const float* __restrict__ bpost,         // 72
    float* __restrict__ out)                 // B x T x 72
{
    const int mt = blockIdx.x;
    const int lane = threadIdx.x;
    const int col = lane & 15;
    const int quad = lane >> 4;

    const short* Ap = Hs + (size_t)(mt * 16 + col) * H + quad * 8;
    const short* Wb = (const short*)Wp;

    f32x4 acc[5];
#pragma unroll
    for (int nt = 0; nt < 5; ++nt) acc[nt] = (f32x4){0.f, 0.f, 0.f, 0.f};

    for (int k = 0; k < H; k += 32) {
        short8 a = ~(*(const short8*)(Ap + k));   // un-invert
#pragma unroll
        for (int nt = 0; nt < 5; ++nt) {
            short8 b = *(const short8*)(Wb + (size_t)(nt * 16 + col) * H + quad * 8 + k);
            acc[nt] = __builtin_amdgcn_mfma_f32_16x16x32_bf16(a, b, acc[nt], 0, 0, 0);
        }
    }

#pragma unroll
    for (int nt = 0; nt < 5; ++nt) {
        const int o = nt * 16 + col;
        if (o < 72) {
            const float bb = bpost[o];
#pragma unroll
            for (int r = 0; r < 4; ++r) {
                const int m = mt * 16 + quad * 4 + r;
                const int t = m >> 8;        // row = t*256 + b
                const int b = m & 255;
                out[((size_t)b * T + t) * 72 + o] = acc[nt][r] + bb;
            }
        }
    }
}

// ---------------- launch ----------------

extern "C" void kernel_launch(void* const* d_in, const int* in_sizes, int n_in,
                              void* d_out, int out_size, void* d_ws, size_t ws_size,
                              hipStream_t stream) {
    const float* src   = (const float*)d_in[0];
    const float* h0    = (const float*)d_in[2];
    const float* c0    = (const float*)d_in[3];
    const float* Wih   = (const float*)d_in[4];
    const float* Whh   = (const float*)d_in[5];
    const float* bih   = (const float*)d_in[6];
    const float* bhh   = (const float*)d_in[7];
    const float* Wpost = (const float*)d_in[8];
    const float* bpost = (const float*)d_in[9];
    float* out = (float*)d_out;

    char* ws = (char*)d_ws;
    __hip_bfloat16* Wcat = (__hip_bfloat16*)(ws + 0);          //  9,437,184 B
    __hip_bfloat16* Wc   = (__hip_bfloat16*)(ws + 9437184);    //  4,718,592 B
    float*          bias = (float*)(ws + 14155776);            //     12,288 B
    __hip_bfloat16* Wp   = (__hip_bfloat16*)(ws + 14168064);   //    122,880 B
    __hip_bfloat16* A0   = (__hip_bfloat16*)(ws + 14290944);   //    786,432 B
    unsigned*       sig  = (unsigned*)(ws + 15863808);         // 39,321,600 B

    // all prep (weights, Wp, A0, sig zero) in one dispatch
    prep_all<<<dim3(3, 9808), 256, 0, stream>>>(src, h0, Wih, Whh, bih, bhh, Wpost,
                                                Wc, Wcat, bias, Wp, A0, (u64*)sig);

    // steps 0..99 in one persistent kernel (batched poll, 4 MFMA chains)
    lstm_persist<<<256, 192, 0, stream>>>(Wc, Wcat, bias, c0, A0, sig);

    proj<<<1600, 64, 0, stream>>>((const short*)sig, Wp, bpost, out);
}

// Round 13
// 575.428 us; speedup vs baseline: 2.5422x; 1.7543x over previous
//
#include <hip/hip_runtime.h>
#include <hip/hip_bf16.h>
#include <math.h>

#define H 768
#define B 256
#define T 100

typedef __attribute__((ext_vector_type(8))) short short8;
typedef __attribute__((ext_vector_type(4))) float f32x4;
typedef unsigned long long u64;

static __device__ __forceinline__ float sigm(float x) {
    return 1.0f / (1.0f + __expf(-x));
}
static __device__ __forceinline__ float tanh_fast(float x) {
    return 1.0f - 2.0f / (__expf(2.0f * x) + 1.0f);
}

// ---------------- fused prep (single dispatch) ----------------
// grid dim3(3, 9808), block 256:
//   y <  3072 : weight row y  (Wc, Wcat, bias)
//   y <  3152 : Wp row (y-3072), zero-padded beyond 72
//   y <  3408 : A0 batch row (y-3152)
//   y <  9808 : sig zero chunk (y-3408): 6400 rows x 768 u64 = 39.3 MB
__global__ void prep_all(const float* __restrict__ src, const float* __restrict__ h0,
                         const float* __restrict__ Wih, const float* __restrict__ Whh,
                         const float* __restrict__ bih, const float* __restrict__ bhh,
                         const float* __restrict__ Wpost,
                         __hip_bfloat16* __restrict__ Wc,    // 3072 x 768 (Wih+Whh)
                         __hip_bfloat16* __restrict__ Wcat,  // 3072 x 1536 [Wih|Whh]
                         float* __restrict__ bias,           // 3072
                         __hip_bfloat16* __restrict__ Wp,    // 80 x 768
                         __hip_bfloat16* __restrict__ A0,    // 256 x 1536 [x0|h0]
                         u64* __restrict__ sig64)            // T*B*192 u64, zeroed
{
    const int bx = blockIdx.x;
    const int y  = blockIdx.y;
    const int k  = bx * 256 + threadIdx.x;
    if (y < 3072) {
        float a = Wih[y * H + k];
        float b = Whh[y * H + k];
        Wc[y * H + k] = __float2bfloat16(a + b);
        Wcat[y * 1536 + k] = __float2bfloat16(a);
        Wcat[y * 1536 + H + k] = __float2bfloat16(b);
        if (bx == 0 && threadIdx.x == 0) bias[y] = bih[y] + bhh[y];
    } else if (y < 3152) {
        int r = y - 3072;
        Wp[r * H + k] = (r < 72) ? __float2bfloat16(Wpost[r * H + k])
                                 : __float2bfloat16(0.0f);
    } else if (y < 3408) {
        int b = y - 3152;
        A0[b * 1536 + k] = __float2bfloat16(src[(b * 16 + 15) * H + k]);  // src[:, -1]
        A0[b * 1536 + H + k] = __float2bfloat16(h0[b * H + k]);
    } else {
        sig64[(size_t)(y - 3408) * 768 + k] = 0ull;
    }
}

// ---------------- persistent recurrence: steps 0..99 ----------------
// R9 skeleton (best verified: 388 us persist): 256 blocks (16 mtg x 16 jg) x
// 768 threads (12 waves = 3 jt x 4 gates), 1 gate/wave, 24 pinned short8.
// R13 deltas: (1) BATCHED poll - all 4 owned sig words loaded back-to-back
// then checked (1 LLC RT/sweep, was ~4 serial); (2) barrier (D) dropped
// ((C) + next-step (B) cover the WAR hazards - protocol validated R11/R12).
#define LDS_H_STRIDE  772    // shorts; 8B-aligned rows, low conflicts (R9-measured)
#define LDS_T0_STRIDE 1540   // shorts
#define XCH_STRIDE    17     // 16 + 1 pad floats

#define LDW8(n0,n1,n2,n3,n4,n5,n6,n7, p) \
    asm volatile("global_load_dwordx4 %0, %8, off\n\t" \
                 "global_load_dwordx4 %1, %8, off offset:64\n\t" \
                 "global_load_dwordx4 %2, %8, off offset:128\n\t" \
                 "global_load_dwordx4 %3, %8, off offset:192\n\t" \
                 "global_load_dwordx4 %4, %8, off offset:256\n\t" \
                 "global_load_dwordx4 %5, %8, off offset:320\n\t" \
                 "global_load_dwordx4 %6, %8, off offset:384\n\t" \
                 "global_load_dwordx4 %7, %8, off offset:448\n\t" \
                 "s_waitcnt vmcnt(0)" \
                 : "=&v"(n0),"=&v"(n1),"=&v"(n2),"=&v"(n3), \
                   "=&v"(n4),"=&v"(n5),"=&v"(n6),"=&v"(n7) \
                 : "v"(p))

#define KSTEP(nm, idx) { \
    short8 a_ = *(const short8*)(&lds_h[col * LDS_H_STRIDE + (idx) * 32 + quad * 8]); \
    acc = __builtin_amdgcn_mfma_f32_16x16x32_bf16(a_, nm, acc, 0, 0, 0); }

static __device__ __forceinline__ bool sig_ok(u64 x) {
    return (unsigned short)x && (unsigned short)(x >> 16) &&
           (unsigned short)(x >> 32) && (unsigned short)(x >> 48);
}

__global__ __launch_bounds__(768, 3) void lstm_persist(
    const __hip_bfloat16* __restrict__ Wc,    // 3072 x 768 bf16 (Wih+Whh)
    const __hip_bfloat16* __restrict__ Wcat,  // 3072 x 1536 bf16 [Wih|Whh]
    const float* __restrict__ bias,           // 3072
    const float* __restrict__ c0in,           // B x H fp32
    const __hip_bfloat16* __restrict__ A0,    // 256 x 1536 [x0|h0]
    unsigned* sig)                            // T x B x 384 u32 (~bf16 pairs), zeroed
{
    const int mtg  = blockIdx.x >> 4;    // batch group 0..15 (16 batches)
    const int jg   = blockIdx.x & 15;    // j group 0..15 (48 j values)
    const int tid  = threadIdx.x;
    const int lane = tid & 63;
    const int wave = tid >> 6;           // 0..11
    const int col  = lane & 15;
    const int quad = lane >> 4;
    const int jt_l = wave >> 2;          // 0..2  local j-tile
    const int gate = wave & 3;           // 0..3  (i,f,g,o)
    const int j    = jg * 48 + jt_l * 16 + col;   // this wave's j column

    __shared__ short lds_h[16 * LDS_T0_STRIDE];   // 49280 B (t0 tile; t>=1 stride 772)
    __shared__ float xch[12 * 16 * XCH_STRIDE];   // 13056 B gate exchange

    // ---- pin resident weight slice (Wc) in regs: 24 x short8 (sound asm) ----
    const short* wptr = (const short*)Wc + (size_t)(gate * H + j) * H + quad * 8;
    short8 w00,w01,w02,w03,w04,w05,w06,w07,w08,w09,w10,w11,
           w12,w13,w14,w15,w16,w17,w18,w19,w20,w21,w22,w23;
    LDW8(w00,w01,w02,w03,w04,w05,w06,w07, wptr);
    LDW8(w08,w09,w10,w11,w12,w13,w14,w15, wptr + 256);
    LDW8(w16,w17,w18,w19,w20,w21,w22,w23, wptr + 512);

    // ---- cell-role state (threads 0..383: two adjacent-j cells each) ----
    const int p    = tid;                 // pair id if < 384 (waves 0..5)
    const int bb   = p / 24;              // local batch 0..15
    const int jp   = p % 24;
    const int jloc = jp * 2;              // local j 0..46 (even)
    const int cjt  = jloc >> 4;           // j-tile of the pair
    const int jcol = jloc & 15;
    const int bglob = mtg * 16 + bb;
    const int jglob = jg * 48 + jloc;
    float c0v = 0.f, c1v = 0.f;
    float bi0=0,bi1=0,bf0=0,bf1=0,bg0=0,bg1=0,bo0=0,bo1=0;
    if (p < 384) {
        c0v = c0in[(size_t)bglob * H + jglob];
        c1v = c0in[(size_t)bglob * H + jglob + 1];
        bi0 = bias[0*H + jglob]; bi1 = bias[0*H + jglob + 1];
        bf0 = bias[1*H + jglob]; bf1 = bias[1*H + jglob + 1];
        bg0 = bias[2*H + jglob]; bg1 = bias[2*H + jglob + 1];
        bo0 = bias[3*H + jglob]; bo1 = bias[3*H + jglob + 1];
    }

    const u64* sig64c = (const u64*)sig;
    const int r0  = tid / 192;    // staging row base 0..3
    const int wrd = tid % 192;    // u64 word within row

    for (int t = 0; t < T; ++t) {
        f32x4 acc = {0.f, 0.f, 0.f, 0.f};

        if (t == 0) {
            // ---- stage A0[16 rows][1536] -> LDS (plain loads; prior kernel) ----
            const u64* a8 = (const u64*)((const short*)A0 + (size_t)(mtg * 16) * 1536);
#pragma unroll
            for (int i = 0; i < 8; ++i) {
                int idx = tid + i * 768;      // 0..6143 (16 rows x 384 u64)
                int br  = idx / 384;
                int ch  = idx % 384;
                *(u64*)&lds_h[br * LDS_T0_STRIDE + ch * 4] = a8[(size_t)br * 384 + ch];
            }
            __syncthreads();   // (B)

            // ---- K=1536 GEMM streaming Wcat (one-time) ----
            const short* wq = (const short*)Wcat + (size_t)(gate * H + j) * 1536 + quad * 8;
            for (int kk = 0; kk < 48; ++kk) {
                short8 a_ = *(const short8*)(&lds_h[col * LDS_T0_STRIDE + kk * 32 + quad * 8]);
                short8 b_ = *(const short8*)(wq + kk * 32);
                acc = __builtin_amdgcn_mfma_f32_16x16x32_bf16(a_, b_, acc, 0, 0, 0);
            }
        } else {
            // ---- poll+stage h(t-1): 4 owned u64 words, BATCHED loads ----
            const u64* hb = sig64c + ((size_t)(t - 1) * B + (size_t)(mtg * 16)) * 192 + wrd;
            u64 x0 = __hip_atomic_load(hb + (size_t)(r0     ) * 192,
                                       __ATOMIC_RELAXED, __HIP_MEMORY_SCOPE_AGENT);
            u64 x1 = __hip_atomic_load(hb + (size_t)(r0 +  4) * 192,
                                       __ATOMIC_RELAXED, __HIP_MEMORY_SCOPE_AGENT);
            u64 x2 = __hip_atomic_load(hb + (size_t)(r0 +  8) * 192,
                                       __ATOMIC_RELAXED, __HIP_MEMORY_SCOPE_AGENT);
            u64 x3 = __hip_atomic_load(hb + (size_t)(r0 + 12) * 192,
                                       __ATOMIC_RELAXED, __HIP_MEMORY_SCOPE_AGENT);
            unsigned pending = 0xFu;
            if (sig_ok(x0)) { *(u64*)&lds_h[(r0     ) * LDS_H_STRIDE + wrd * 4] = ~x0; pending &= ~1u; }
            if (sig_ok(x1)) { *(u64*)&lds_h[(r0 +  4) * LDS_H_STRIDE + wrd * 4] = ~x1; pending &= ~2u; }
            if (sig_ok(x2)) { *(u64*)&lds_h[(r0 +  8) * LDS_H_STRIDE + wrd * 4] = ~x2; pending &= ~4u; }
            if (sig_ok(x3)) { *(u64*)&lds_h[(r0 + 12) * LDS_H_STRIDE + wrd * 4] = ~x3; pending &= ~8u; }
            int guard = 0;
            while (pending && ++guard < (1 << 22)) {
                __builtin_amdgcn_s_sleep(1);
                // re-issue all pending loads back-to-back, then check
                if (pending & 1u) x0 = __hip_atomic_load(hb + (size_t)(r0     ) * 192,
                                        __ATOMIC_RELAXED, __HIP_MEMORY_SCOPE_AGENT);
                if (pending & 2u) x1 = __hip_atomic_load(hb + (size_t)(r0 +  4) * 192,
                                        __ATOMIC_RELAXED, __HIP_MEMORY_SCOPE_AGENT);
                if (pending & 4u) x2 = __hip_atomic_load(hb + (size_t)(r0 +  8) * 192,
                                        __ATOMIC_RELAXED, __HIP_MEMORY_SCOPE_AGENT);
                if (pending & 8u) x3 = __hip_atomic_load(hb + (size_t)(r0 + 12) * 192,
                                        __ATOMIC_RELAXED, __HIP_MEMORY_SCOPE_AGENT);
                if ((pending & 1u) && sig_ok(x0)) { *(u64*)&lds_h[(r0     ) * LDS_H_STRIDE + wrd * 4] = ~x0; pending &= ~1u; }
                if ((pending & 2u) && sig_ok(x1)) { *(u64*)&lds_h[(r0 +  4) * LDS_H_STRIDE + wrd * 4] = ~x1; pending &= ~2u; }
                if ((pending & 4u) && sig_ok(x2)) { *(u64*)&lds_h[(r0 +  8) * LDS_H_STRIDE + wrd * 4] = ~x2; pending &= ~4u; }
                if ((pending & 8u) && sig_ok(x3)) { *(u64*)&lds_h[(r0 + 12) * LDS_H_STRIDE + wrd * 4] = ~x3; pending &= ~8u; }
            }
            __syncthreads();   // (B) lds_h ready

            // ---- K=768 GEMM vs pinned weights ----
            KSTEP(w00,0)  KSTEP(w01,1)  KSTEP(w02,2)  KSTEP(w03,3)
            KSTEP(w04,4)  KSTEP(w05,5)  KSTEP(w06,6)  KSTEP(w07,7)
            KSTEP(w08,8)  KSTEP(w09,9)  KSTEP(w10,10) KSTEP(w11,11)
            KSTEP(w12,12) KSTEP(w13,13) KSTEP(w14,14) KSTEP(w15,15)
            KSTEP(w16,16) KSTEP(w17,17) KSTEP(w18,18) KSTEP(w19,19)
            KSTEP(w20,20) KSTEP(w21,21) KSTEP(w22,22) KSTEP(w23,23)
        }

        // ---- exchange gate tiles through LDS ----
        float* xw = &xch[(size_t)wave * 16 * XCH_STRIDE];
#pragma unroll
        for (int r = 0; r < 4; ++r)
            xw[(quad * 4 + r) * XCH_STRIDE + col] = acc[r];
        __syncthreads();   // (C) xch ready; all lds_h reads of this step done

        // ---- cell update + inverted-bf16 publish (store IS the signal) ----
        if (p < 384) {
            const float* xg = &xch[(size_t)(cjt * 4) * 16 * XCH_STRIDE + bb * XCH_STRIDE + jcol];
            const int gs = 16 * XCH_STRIDE;
            float i0 = xg[0*gs] + bi0, i1 = xg[0*gs + 1] + bi1;
            float f0 = xg[1*gs] + bf0, f1 = xg[1*gs + 1] + bf1;
            float g0 = xg[2*gs] + bg0, g1 = xg[2*gs + 1] + bg1;
            float o0 = xg[3*gs] + bo0, o1 = xg[3*gs + 1] + bo1;
            float cn0 = sigm(f0) * c0v + sigm(i0) * tanh_fast(g0);
            float cn1 = sigm(f1) * c1v + sigm(i1) * tanh_fast(g1);
            c0v = cn0; c1v = cn1;
            __hip_bfloat16 h0b = __float2bfloat16(sigm(o0) * tanh_fast(cn0));
            __hip_bfloat16 h1b = __float2bfloat16(sigm(o1) * tanh_fast(cn1));
            unsigned lo = (unsigned)(unsigned short)~(*(unsigned short*)&h0b);  // nonzero
            unsigned hi = (unsigned)(unsigned short)~(*(unsigned short*)&h1b);  // nonzero
            __hip_atomic_store(&sig[((size_t)t * B + bglob) * 384 + (jglob >> 1)],
                               lo | (hi << 16),
                               __ATOMIC_RELAXED, __HIP_MEMORY_SCOPE_AGENT);
        }
        // no barrier (D): (C) + next-step (B) cover the WAR hazards.
    }
}

// ---------------- post projection (reads inverted sig) ----------------
__global__ __launch_bounds__(64) void proj(
    const short* __restrict__ Hs,            // (T*B) x 768 inverted bf16
    const __hip_bfloat16* __restrict__ Wp,   // 80 x H (padded bf16)
    const float* __restrict__ bpost,         // 72
    float* __restrict__ out)                 // B x T x 72
{
    const int mt = blockIdx.x;
    const int lane = threadIdx.x;
    const int col = lane & 15;
    const int quad = lane >> 4;

    const short* Ap = Hs + (size_t)(mt * 16 + col) * H + quad * 8;
    const short* Wb = (const short*)Wp;

    f32x4 acc[5];
#pragma unroll
    for (int nt = 0; nt < 5; ++nt) acc[nt] = (f32x4){0.f, 0.f, 0.f, 0.f};

    for (int k = 0; k < H; k += 32) {
        short8 a = ~(*(const short8*)(Ap + k));   // un-invert
#pragma unroll
        for (int nt = 0; nt < 5; ++nt) {
            short8 b = *(const short8*)(Wb + (size_t)(nt * 16 + col) * H + quad * 8 + k);
            acc[nt] = __builtin_amdgcn_mfma_f32_16x16x32_bf16(a, b, acc[nt], 0, 0, 0);
        }
    }

#pragma unroll
    for (int nt = 0; nt < 5; ++nt) {
        const int o = nt * 16 + col;
        if (o < 72) {
            const float bb = bpost[o];
#pragma unroll
            for (int r = 0; r < 4; ++r) {
                const int m = mt * 16 + quad * 4 + r;
                const int t = m >> 8;        // row = t*256 + b
                const int b = m & 255;
                out[((size_t)b * T + t) * 72 + o] = acc[nt][r] + bb;
            }
        }
    }
}

// ---------------- launch ----------------

extern "C" void kernel_launch(void* const* d_in, const int* in_sizes, int n_in,
                              void* d_out, int out_size, void* d_ws, size_t ws_size,
                              hipStream_t stream) {
    const float* src   = (const float*)d_in[0];
    const float* h0    = (const float*)d_in[2];
    const float* c0    = (const float*)d_in[3];
    const float* Wih   = (const float*)d_in[4];
    const float* Whh   = (const float*)d_in[5];
    const float* bih   = (const float*)d_in[6];
    const float* bhh   = (const float*)d_in[7];
    const float* Wpost = (const float*)d_in[8];
    const float* bpost = (const float*)d_in[9];
    float* out = (float*)d_out;

    char* ws = (char*)d_ws;
    __hip_bfloat16* Wcat = (__hip_bfloat16*)(ws + 0);          //  9,437,184 B
    __hip_bfloat16* Wc   = (__hip_bfloat16*)(ws + 9437184);    //  4,718,592 B
    float*          bias = (float*)(ws + 14155776);            //     12,288 B
    __hip_bfloat16* Wp   = (__hip_bfloat16*)(ws + 14168064);   //    122,880 B
    __hip_bfloat16* A0   = (__hip_bfloat16*)(ws + 14290944);   //    786,432 B
    unsigned*       sig  = (unsigned*)(ws + 15863808);         // 39,321,600 B

    // all prep (weights, Wp, A0, sig zero) in one dispatch
    prep_all<<<dim3(3, 9808), 256, 0, stream>>>(src, h0, Wih, Whh, bih, bhh, Wpost,
                                                Wc, Wcat, bias, Wp, A0, (u64*)sig);

    // steps 0..99 in one persistent kernel (R9 skeleton + batched poll, no (D))
    lstm_persist<<<256, 768, 0, stream>>>(Wc, Wcat, bias, c0, A0, sig);

    proj<<<1600, 64, 0, stream>>>((const short*)sig, Wp, bpost, out);
}

// Round 14
// 460.029 us; speedup vs baseline: 3.1799x; 1.2509x over previous
//
#include <hip/hip_runtime.h>
#include <hip/hip_bf16.h>
#include <math.h>

#define H 768
#define B 256
#define T 100

typedef __attribute__((ext_vector_type(8))) short short8;
typedef __attribute__((ext_vector_type(4))) float f32x4;
typedef unsigned long long u64;

static __device__ __forceinline__ float sigm(float x) {
    return 1.0f / (1.0f + __expf(-x));
}
static __device__ __forceinline__ float tanh_fast(float x) {
    return 1.0f - 2.0f / (__expf(2.0f * x) + 1.0f);
}

// ---------------- fused prep (single dispatch) ----------------
// grid dim3(3, 9808), block 256:
//   y <  3072 : weight row y  (Wc, Wcat, bias)
//   y <  3152 : Wp row (y-3072), zero-padded beyond 72
//   y <  3408 : A0 batch row (y-3152)
//   y <  9808 : sig zero chunk (y-3408): 6400 rows x 768 u64 = 39.3 MB
__global__ void prep_all(const float* __restrict__ src, const float* __restrict__ h0,
                         const float* __restrict__ Wih, const float* __restrict__ Whh,
                         const float* __restrict__ bih, const float* __restrict__ bhh,
                         const float* __restrict__ Wpost,
                         __hip_bfloat16* __restrict__ Wc,    // 3072 x 768 (Wih+Whh)
                         __hip_bfloat16* __restrict__ Wcat,  // 3072 x 1536 [Wih|Whh]
                         float* __restrict__ bias,           // 3072
                         __hip_bfloat16* __restrict__ Wp,    // 80 x 768
                         __hip_bfloat16* __restrict__ A0,    // 256 x 1536 [x0|h0]
                         u64* __restrict__ sig64)            // T*B*192 u64, zeroed
{
    const int bx = blockIdx.x;
    const int y  = blockIdx.y;
    const int k  = bx * 256 + threadIdx.x;
    if (y < 3072) {
        float a = Wih[y * H + k];
        float b = Whh[y * H + k];
        Wc[y * H + k] = __float2bfloat16(a + b);
        Wcat[y * 1536 + k] = __float2bfloat16(a);
        Wcat[y * 1536 + H + k] = __float2bfloat16(b);
        if (bx == 0 && threadIdx.x == 0) bias[y] = bih[y] + bhh[y];
    } else if (y < 3152) {
        int r = y - 3072;
        Wp[r * H + k] = (r < 72) ? __float2bfloat16(Wpost[r * H + k])
                                 : __float2bfloat16(0.0f);
    } else if (y < 3408) {
        int b = y - 3152;
        A0[b * 1536 + k] = __float2bfloat16(src[(b * 16 + 15) * H + k]);  // src[:, -1]
        A0[b * 1536 + H + k] = __float2bfloat16(h0[b * H + k]);
    } else {
        sig64[(size_t)(y - 3408) * 768 + k] = 0ull;
    }
}

// ---------------- persistent recurrence: steps 0..99 ----------------
// R9 skeleton: 256 blocks (16 mtg x 16 jg) x 768 threads (12 waves = 3 jt x
// 4 gates), 1 gate/wave, 24 pinned short8 (sound grouped-asm loads).
// R14: batched poll (R13) + barrier (D) RESTORED (it is the poll throttle -
// without it idle waves flood the LLC with early polls and delay the very
// h stores they wait on: R13 FETCH 164->291 MB, +73us/step) + retry sleep
// s_sleep(4) to keep sweep rate at R9 levels despite cheaper batched sweeps.
#define LDS_H_STRIDE  772    // shorts; 8B-aligned rows, low conflicts (R9-measured)
#define LDS_T0_STRIDE 1540   // shorts
#define XCH_STRIDE    17     // 16 + 1 pad floats

#define LDW8(n0,n1,n2,n3,n4,n5,n6,n7, p) \
    asm volatile("global_load_dwordx4 %0, %8, off\n\t" \
                 "global_load_dwordx4 %1, %8, off offset:64\n\t" \
                 "global_load_dwordx4 %2, %8, off offset:128\n\t" \
                 "global_load_dwordx4 %3, %8, off offset:192\n\t" \
                 "global_load_dwordx4 %4, %8, off offset:256\n\t" \
                 "global_load_dwordx4 %5, %8, off offset:320\n\t" \
                 "global_load_dwordx4 %6, %8, off offset:384\n\t" \
                 "global_load_dwordx4 %7, %8, off offset:448\n\t" \
                 "s_waitcnt vmcnt(0)" \
                 : "=&v"(n0),"=&v"(n1),"=&v"(n2),"=&v"(n3), \
                   "=&v"(n4),"=&v"(n5),"=&v"(n6),"=&v"(n7) \
                 : "v"(p))

#define KSTEP(nm, idx) { \
    short8 a_ = *(const short8*)(&lds_h[col * LDS_H_STRIDE + (idx) * 32 + quad * 8]); \
    acc = __builtin_amdgcn_mfma_f32_16x16x32_bf16(a_, nm, acc, 0, 0, 0); }

static __device__ __forceinline__ bool sig_ok(u64 x) {
    return (unsigned short)x && (unsigned short)(x >> 16) &&
           (unsigned short)(x >> 32) && (unsigned short)(x >> 48);
}

__global__ __launch_bounds__(768, 3) void lstm_persist(
    const __hip_bfloat16* __restrict__ Wc,    // 3072 x 768 bf16 (Wih+Whh)
    const __hip_bfloat16* __restrict__ Wcat,  // 3072 x 1536 bf16 [Wih|Whh]
    const float* __restrict__ bias,           // 3072
    const float* __restrict__ c0in,           // B x H fp32
    const __hip_bfloat16* __restrict__ A0,    // 256 x 1536 [x0|h0]
    unsigned* sig)                            // T x B x 384 u32 (~bf16 pairs), zeroed
{
    const int mtg  = blockIdx.x >> 4;    // batch group 0..15 (16 batches)
    const int jg   = blockIdx.x & 15;    // j group 0..15 (48 j values)
    const int tid  = threadIdx.x;
    const int lane = tid & 63;
    const int wave = tid >> 6;           // 0..11
    const int col  = lane & 15;
    const int quad = lane >> 4;
    const int jt_l = wave >> 2;          // 0..2  local j-tile
    const int gate = wave & 3;           // 0..3  (i,f,g,o)
    const int j    = jg * 48 + jt_l * 16 + col;   // this wave's j column

    __shared__ short lds_h[16 * LDS_T0_STRIDE];   // 49280 B (t0 tile; t>=1 stride 772)
    __shared__ float xch[12 * 16 * XCH_STRIDE];   // 13056 B gate exchange

    // ---- pin resident weight slice (Wc) in regs: 24 x short8 (sound asm) ----
    const short* wptr = (const short*)Wc + (size_t)(gate * H + j) * H + quad * 8;
    short8 w00,w01,w02,w03,w04,w05,w06,w07,w08,w09,w10,w11,
           w12,w13,w14,w15,w16,w17,w18,w19,w20,w21,w22,w23;
    LDW8(w00,w01,w02,w03,w04,w05,w06,w07, wptr);
    LDW8(w08,w09,w10,w11,w12,w13,w14,w15, wptr + 256);
    LDW8(w16,w17,w18,w19,w20,w21,w22,w23, wptr + 512);

    // ---- cell-role state (threads 0..383: two adjacent-j cells each) ----
    const int p    = tid;                 // pair id if < 384 (waves 0..5)
    const int bb   = p / 24;              // local batch 0..15
    const int jp   = p % 24;
    const int jloc = jp * 2;              // local j 0..46 (even)
    const int cjt  = jloc >> 4;           // j-tile of the pair
    const int jcol = jloc & 15;
    const int bglob = mtg * 16 + bb;
    const int jglob = jg * 48 + jloc;
    float c0v = 0.f, c1v = 0.f;
    float bi0=0,bi1=0,bf0=0,bf1=0,bg0=0,bg1=0,bo0=0,bo1=0;
    if (p < 384) {
        c0v = c0in[(size_t)bglob * H + jglob];
        c1v = c0in[(size_t)bglob * H + jglob + 1];
        bi0 = bias[0*H + jglob]; bi1 = bias[0*H + jglob + 1];
        bf0 = bias[1*H + jglob]; bf1 = bias[1*H + jglob + 1];
        bg0 = bias[2*H + jglob]; bg1 = bias[2*H + jglob + 1];
        bo0 = bias[3*H + jglob]; bo1 = bias[3*H + jglob + 1];
    }

    const u64* sig64c = (const u64*)sig;
    const int r0  = tid / 192;    // staging row base 0..3
    const int wrd = tid % 192;    // u64 word within row

    for (int t = 0; t < T; ++t) {
        f32x4 acc = {0.f, 0.f, 0.f, 0.f};

        if (t == 0) {
            // ---- stage A0[16 rows][1536] -> LDS (plain loads; prior kernel) ----
            const u64* a8 = (const u64*)((const short*)A0 + (size_t)(mtg * 16) * 1536);
#pragma unroll
            for (int i = 0; i < 8; ++i) {
                int idx = tid + i * 768;      // 0..6143 (16 rows x 384 u64)
                int br  = idx / 384;
                int ch  = idx % 384;
                *(u64*)&lds_h[br * LDS_T0_STRIDE + ch * 4] = a8[(size_t)br * 384 + ch];
            }
            __syncthreads();   // (B)

            // ---- K=1536 GEMM streaming Wcat (one-time) ----
            const short* wq = (const short*)Wcat + (size_t)(gate * H + j) * 1536 + quad * 8;
            for (int kk = 0; kk < 48; ++kk) {
                short8 a_ = *(const short8*)(&lds_h[col * LDS_T0_STRIDE + kk * 32 + quad * 8]);
                short8 b_ = *(const short8*)(wq + kk * 32);
                acc = __builtin_amdgcn_mfma_f32_16x16x32_bf16(a_, b_, acc, 0, 0, 0);
            }
        } else {
            // ---- poll+stage h(t-1): 4 owned u64 words, BATCHED loads ----
            const u64* hb = sig64c + ((size_t)(t - 1) * B + (size_t)(mtg * 16)) * 192 + wrd;
            u64 x0 = __hip_atomic_load(hb + (size_t)(r0     ) * 192,
                                       __ATOMIC_RELAXED, __HIP_MEMORY_SCOPE_AGENT);
            u64 x1 = __hip_atomic_load(hb + (size_t)(r0 +  4) * 192,
                                       __ATOMIC_RELAXED, __HIP_MEMORY_SCOPE_AGENT);
            u64 x2 = __hip_atomic_load(hb + (size_t)(r0 +  8) * 192,
                                       __ATOMIC_RELAXED, __HIP_MEMORY_SCOPE_AGENT);
            u64 x3 = __hip_atomic_load(hb + (size_t)(r0 + 12) * 192,
                                       __ATOMIC_RELAXED, __HIP_MEMORY_SCOPE_AGENT);
            unsigned pending = 0xFu;
            if (sig_ok(x0)) { *(u64*)&lds_h[(r0     ) * LDS_H_STRIDE + wrd * 4] = ~x0; pending &= ~1u; }
            if (sig_ok(x1)) { *(u64*)&lds_h[(r0 +  4) * LDS_H_STRIDE + wrd * 4] = ~x1; pending &= ~2u; }
            if (sig_ok(x2)) { *(u64*)&lds_h[(r0 +  8) * LDS_H_STRIDE + wrd * 4] = ~x2; pending &= ~4u; }
            if (sig_ok(x3)) { *(u64*)&lds_h[(r0 + 12) * LDS_H_STRIDE + wrd * 4] = ~x3; pending &= ~8u; }
            int guard = 0;
            while (pending && ++guard < (1 << 22)) {
                __builtin_amdgcn_s_sleep(4);   // throttle: ~256 cyc between sweeps
                if (pending & 1u) x0 = __hip_atomic_load(hb + (size_t)(r0     ) * 192,
                                        __ATOMIC_RELAXED, __HIP_MEMORY_SCOPE_AGENT);
                if (pending & 2u) x1 = __hip_atomic_load(hb + (size_t)(r0 +  4) * 192,
                                        __ATOMIC_RELAXED, __HIP_MEMORY_SCOPE_AGENT);
                if (pending & 4u) x2 = __hip_atomic_load(hb + (size_t)(r0 +  8) * 192,
                                        __ATOMIC_RELAXED, __HIP_MEMORY_SCOPE_AGENT);
                if (pending & 8u) x3 = __hip_atomic_load(hb + (size_t)(r0 + 12) * 192,
                                        __ATOMIC_RELAXED, __HIP_MEMORY_SCOPE_AGENT);
                if ((pending & 1u) && sig_ok(x0)) { *(u64*)&lds_h[(r0     ) * LDS_H_STRIDE + wrd * 4] = ~x0; pending &= ~1u; }
                if ((pending & 2u) && sig_ok(x1)) { *(u64*)&lds_h[(r0 +  4) * LDS_H_STRIDE + wrd * 4] = ~x1; pending &= ~2u; }
                if ((pending & 4u) && sig_ok(x2)) { *(u64*)&lds_h[(r0 +  8) * LDS_H_STRIDE + wrd * 4] = ~x2; pending &= ~4u; }
                if ((pending & 8u) && sig_ok(x3)) { *(u64*)&lds_h[(r0 + 12) * LDS_H_STRIDE + wrd * 4] = ~x3; pending &= ~8u; }
            }
            __syncthreads();   // (B) lds_h ready

            // ---- K=768 GEMM vs pinned weights ----
            KSTEP(w00,0)  KSTEP(w01,1)  KSTEP(w02,2)  KSTEP(w03,3)
            KSTEP(w04,4)  KSTEP(w05,5)  KSTEP(w06,6)  KSTEP(w07,7)
            KSTEP(w08,8)  KSTEP(w09,9)  KSTEP(w10,10) KSTEP(w11,11)
            KSTEP(w12,12) KSTEP(w13,13) KSTEP(w14,14) KSTEP(w15,15)
            KSTEP(w16,16) KSTEP(w17,17) KSTEP(w18,18) KSTEP(w19,19)
            KSTEP(w20,20) KSTEP(w21,21) KSTEP(w22,22) KSTEP(w23,23)
        }

        // ---- exchange gate tiles through LDS ----
        float* xw = &xch[(size_t)wave * 16 * XCH_STRIDE];
#pragma unroll
        for (int r = 0; r < 4; ++r)
            xw[(quad * 4 + r) * XCH_STRIDE + col] = acc[r];
        __syncthreads();   // (C) xch ready; all lds_h reads of this step done

        // ---- cell update + inverted-bf16 publish (store IS the signal) ----
        if (p < 384) {
            const float* xg = &xch[(size_t)(cjt * 4) * 16 * XCH_STRIDE + bb * XCH_STRIDE + jcol];
            const int gs = 16 * XCH_STRIDE;
            float i0 = xg[0*gs] + bi0, i1 = xg[0*gs + 1] + bi1;
            float f0 = xg[1*gs] + bf0, f1 = xg[1*gs + 1] + bf1;
            float g0 = xg[2*gs] + bg0, g1 = xg[2*gs + 1] + bg1;
            float o0 = xg[3*gs] + bo0, o1 = xg[3*gs + 1] + bo1;
            float cn0 = sigm(f0) * c0v + sigm(i0) * tanh_fast(g0);
            float cn1 = sigm(f1) * c1v + sigm(i1) * tanh_fast(g1);
            c0v = cn0; c1v = cn1;
            __hip_bfloat16 h0b = __float2bfloat16(sigm(o0) * tanh_fast(cn0));
            __hip_bfloat16 h1b = __float2bfloat16(sigm(o1) * tanh_fast(cn1));
            unsigned lo = (unsigned)(unsigned short)~(*(unsigned short*)&h0b);  // nonzero
            unsigned hi = (unsigned)(unsigned short)~(*(unsigned short*)&h1b);  // nonzero
            __hip_atomic_store(&sig[((size_t)t * B + bglob) * 384 + (jglob >> 1)],
                               lo | (hi << 16),
                               __ATOMIC_RELAXED, __HIP_MEMORY_SCOPE_AGENT);
        }
        __syncthreads();   // (D) poll throttle: park all waves until publish done
    }
}

// ---------------- post projection (reads inverted sig) ----------------
__global__ __launch_bounds__(64) void proj(
    const short* __restrict__ Hs,            // (T*B) x 768 inverted bf16
    const __hip_bfloat16* __restrict__ Wp,   // 80 x H (padded bf16)
    const float* __restrict__ bpost,         // 72
    float* __restrict__ out)                 // B x T x 72
{
    const int mt = blockIdx.x;
    const int lane = threadIdx.x;
    const int col = lane & 15;
    const int quad = lane >> 4;

    const short* Ap = Hs + (size_t)(mt * 16 + col) * H + quad * 8;
    const short* Wb = (const short*)Wp;

    f32x4 acc[5];
#pragma unroll
    for (int nt = 0; nt < 5; ++nt) acc[nt] = (f32x4){0.f, 0.f, 0.f, 0.f};

    for (int k = 0; k < H; k += 32) {
        short8 a = ~(*(const short8*)(Ap + k));   // un-invert
#pragma unroll
        for (int nt = 0; nt < 5; ++nt) {
            short8 b = *(const short8*)(Wb + (size_t)(nt * 16 + col) * H + quad * 8 + k);
            acc[nt] = __builtin_amdgcn_mfma_f32_16x16x32_bf16(a, b, acc[nt], 0, 0, 0);
        }
    }

#pragma unroll
    for (int nt = 0; nt < 5; ++nt) {
        const int o = nt * 16 + col;
        if (o < 72) {
            const float bb = bpost[o];
#pragma unroll
            for (int r = 0; r < 4; ++r) {
                const int m = mt * 16 + quad * 4 + r;
                const int t = m >> 8;        // row = t*256 + b
                const int b = m & 255;
                out[((size_t)b * T + t) * 72 + o] = acc[nt][r] + bb;
            }
        }
    }
}

// ---------------- launch ----------------

extern "C" void kernel_launch(void* const* d_in, const int* in_sizes, int n_in,
                              void* d_out, int out_size, void* d_ws, size_t ws_size,
                              hipStream_t stream) {
    const float* src   = (const float*)d_in[0];
    const float* h0    = (const float*)d_in[2];
    const float* c0    = (const float*)d_in[3];
    const float* Wih   = (const float*)d_in[4];
    const float* Whh   = (const float*)d_in[5];
    const float* bih   = (const float*)d_in[6];
    const float* bhh   = (const float*)d_in[7];
    const float* Wpost = (const float*)d_in[8];
    const float* bpost = (const float*)d_in[9];
    float* out = (float*)d_out;

    char* ws = (char*)d_ws;
    __hip_bfloat16* Wcat = (__hip_bfloat16*)(ws + 0);          //  9,437,184 B
    __hip_bfloat16* Wc   = (__hip_bfloat16*)(ws + 9437184);    //  4,718,592 B
    float*          bias = (float*)(ws + 14155776);            //     12,288 B
    __hip_bfloat16* Wp   = (__hip_bfloat16*)(ws + 14168064);   //    122,880 B
    __hip_bfloat16* A0   = (__hip_bfloat16*)(ws + 14290944);   //    786,432 B
    unsigned*       sig  = (unsigned*)(ws + 15863808);         // 39,321,600 B

    // all prep (weights, Wp, A0, sig zero) in one dispatch
    prep_all<<<dim3(3, 9808), 256, 0, stream>>>(src, h0, Wih, Whh, bih, bhh, Wpost,
                                                Wc, Wcat, bias, Wp, A0, (u64*)sig);

    // steps 0..99 in one persistent kernel (R9 + batched poll + (D) throttle)
    lstm_persist<<<256, 768, 0, stream>>>(Wc, Wcat, bias, c0, A0, sig);

    proj<<<1600, 64, 0, stream>>>((const short*)sig, Wp, bpost, out);
}